// Round 1
// baseline (4799.673 us; speedup 1.0000x reference)
//
#include <hip/hip_runtime.h>
#include <math.h>
#include <utility>

#define TB 1024   // batch
#define HH 100    // hidden
#define GG 300    // 3*H gate rows

// ---------------------------------------------------------------------------
// NUMERICS ARE FROZEN — DO NOT TOUCH.
// R1 (__expf), R5 (naive exp2), R6 (1-ulp Cody-Waite expm1) ALL flipped the
// same decoder argmax site (absmax=14). Only the ocml expf/tanhf profile
// (R2/R3/R7/R8/R9) lands on the reference side of a knife-edge logit
// near-tie. The transcendentals AND the per-element GEMV/gate expression DAG
// (values, pairing, order) must stay bit-identical. Perf work value-neutral.
//
// R11: structural rework, DAG-identical. Old: 640 thr (2 teams x 300 rows),
// BT=2, whh in LDS (k-packed), wih in regs (SPILLED for K=100: VGPR=84).
// Counters showed joint VALU(74%)+LDS saturation; lane-varying whh ds_reads
// (~12cyc each) + 10 waves of broadcast reads = ~7000 LDS cyc/step.
// New: 320 thr (1 team x 300 rows), BT=4, BOTH wih and whh rows in VGPRs
// (launch_bounds(320,2) -> cap 256; ~230 used for K=100). This removes ALL
// lane-varying LDS reads from the step loop; only cheap uniform broadcasts
// of x_s/h_s remain (count unchanged vs old: waves*25*BT invariant).
// gemv4 is used for BOTH GEMVs -> identical expression tree, identical
// pairing w[4g+j]*v[4g+j], identical left-assoc FMA contraction as before.
// ---------------------------------------------------------------------------
__device__ __forceinline__ float sigmoidf_(float x) {
    return 1.0f / (1.0f + expf(-x));
}
__device__ __forceinline__ float tanhf_(float x) {
    return tanhf(x);
}

template<size_t... Is>
__device__ __forceinline__ void ldN(std::index_sequence<Is...>,
                                    float* __restrict__ dst,
                                    const float* __restrict__ src) {
    ((dst[Is] = src[Is]), ...);
}
__device__ __forceinline__ float pin_val(float v) {
    asm volatile("" : "+v"(v));
    return v;
}
// IN-LOOP PIN (R10, kept): non-rematerializable SSA chain -> weights stay
// VGPR-resident across the time loop. Emits ZERO instructions.
template<size_t... Is>
__device__ __forceinline__ void pinN(std::index_sequence<Is...>, float* w) {
    ((w[Is] = pin_val(w[Is])), ...);
}

// acc += w-row (registers) dot vec (LDS broadcast), float4-grouped.
// EXACT expression shape shared by acc_i and acc_h paths (frozen DAG).
template<int KK, int BT, int LD>
__device__ __forceinline__ void fma_step(const float* __restrict__ w,
                                         const float (*xs)[LD],
                                         float* __restrict__ acc) {
    #pragma unroll
    for (int b = 0; b < BT; ++b) {
        const float4 xv = *reinterpret_cast<const float4*>(&xs[b][KK]);
        acc[b] += w[KK]     * xv.x + w[KK + 1] * xv.y
                + w[KK + 2] * xv.z + w[KK + 3] * xv.w;
    }
}
template<int BT, int LD, size_t... Is>
__device__ __forceinline__ void gemv4(std::index_sequence<Is...>,
                                      const float* __restrict__ w,
                                      const float (*xs)[LD],
                                      float* __restrict__ acc) {
    (fma_step<(int)(Is * 4), BT, LD>(w, xs, acc), ...);
}

// Persistent GRU layer kernel. grid=256 blocks, block=320 threads (5 waves).
// Thread = one gate-row (0..299, 20 pad), BT=4 batch elems per block.
// wih row AND whh row live in VGPRs; LDS holds only h/x/r/z (+emb) buffers.
template<int K, bool EMB, bool WRITE_SEQ>
__global__ __launch_bounds__(320, 2)
void gru_kernel(const float* __restrict__ xin,   // [T,B,K] (if !EMB)
                const int*   __restrict__ tgt,   // [T,B]   (if EMB)
                const float* __restrict__ emb,   // [64,26] (if EMB)
                const float* __restrict__ Wih,   // [300,K]
                const float* __restrict__ Whh,   // [300,100]
                const float* __restrict__ bih,
                const float* __restrict__ bhh,
                const float* __restrict__ h_init,// [B,100] or null -> zeros
                float* __restrict__ seq_out,     // [T,B,100] (if WRITE_SEQ)
                float* __restrict__ h_last,      // [B,100] or null
                int T)
{
    constexpr int KP = (K + 3) & ~3;   // 28 or 100
    constexpr int BT = 4;              // batch per block
    static_assert(KP % 4 == 0, "");

    const int tj  = threadIdx.x;       // row index (0..319)
    const int bb0 = blockIdx.x * BT;
    const int g   = tj / 100;
    const int i   = tj % 100;

    __shared__ __align__(16) float h_s[BT][HH];
    __shared__ __align__(16) float x_s[BT][KP];
    __shared__ float r_s[BT][HH];
    __shared__ float z_s[BT][HH];
    __shared__ float emb_s[EMB ? 64 : 1][EMB ? 28 : 4];
    __shared__ int   tgt_s[BT];

    // ---- wih + whh rows into registers (one-time, clamped row for pads) ----
    const int jj = (tj < GG) ? tj : 0;
    float wih[KP];
    ldN(std::make_index_sequence<K>{}, wih, Wih + (long)jj * K);
    #pragma unroll
    for (int k = K; k < KP; ++k) wih[k] = 0.f;
    float whr[HH];
    ldN(std::make_index_sequence<HH>{}, whr, Whh + (long)jj * HH);
    float bi = bih[jj];
    float bh = bhh[jj];

    // ---- init h ----
    for (int idx = tj; idx < BT * HH; idx += 320) {
        int b = idx / HH, k = idx % HH;
        h_s[b][k] = h_init ? h_init[(bb0 + b) * HH + k] : 0.f;
    }
    // ---- init x_s for t=0 ----
    if constexpr (EMB) {
        for (int idx = tj; idx < 64 * 28; idx += 320) {
            int d = idx / 28, k = idx % 28;
            emb_s[d][k] = (k < 26) ? emb[d * 26 + k] : 0.f;
        }
        __syncthreads();
        for (int idx = tj; idx < BT * KP; idx += 320) {
            int b = idx / KP, k = idx % KP;
            int t0 = tgt[bb0 + b];
            x_s[b][k] = emb_s[t0][k];    // pads are 0 via emb_s
        }
    } else {
        for (int idx = tj; idx < BT * KP; idx += 320) {
            int b = idx / KP, k = idx % KP;
            x_s[b][k] = (k < K) ? xin[(bb0 + b) * K + k] : 0.f;
        }
    }
    __syncthreads();   // h_s, x_s ready

    // ---- time loop ----
    for (int t = 0; t < T; ++t) {
        // IN-LOOP PIN: both weight rows stay VGPR-resident (no remat/spill).
        pinN(std::make_index_sequence<KP>{}, wih);
        pinN(std::make_index_sequence<HH>{}, whr);
        bi = pin_val(bi);
        bh = pin_val(bh);

        const bool has_next = (t + 1 < T);

        // prefetch next step's input into regs (hidden under FMA loop)
        float px0 = 0.f, px1 = 0.f;
        int   ptg = 0;
        if constexpr (!EMB) {
            if (has_next) {
                if (tj < BT * K)
                    px0 = xin[((t + 1) * TB + bb0 + tj / K) * K + tj % K];
                if constexpr (BT * K > 320) {
                    if (tj + 320 < BT * K)
                        px1 = xin[((t + 1) * TB + bb0 + (tj + 320) / K) * K
                                  + (tj + 320) % K];
                }
            }
        } else {
            if (has_next && tj < BT) ptg = tgt[(t + 1) * TB + bb0 + tj];
        }

        // main GEMV: acc_i = Wih[j,:].x + bi ; acc_h = Whh[j,:].h + bh
        float acc_i[BT], acc_h[BT];
        #pragma unroll
        for (int b = 0; b < BT; ++b) { acc_i[b] = bi; acc_h[b] = bh; }

        gemv4<BT, KP>(std::make_index_sequence<KP / 4>{}, wih, x_s, acc_i);
        gemv4<BT, HH>(std::make_index_sequence<HH / 4>{}, whr, h_s, acc_h);

        // r / z gates -> LDS
        if (tj < 200) {
            #pragma unroll
            for (int b = 0; b < BT; ++b) {
                float v = sigmoidf_(acc_i[b] + acc_h[b]);
                if (g == 0) r_s[b][i] = v;
                else        z_s[b][i] = v;
            }
        }
        __syncthreads();   // B1: gates visible; h_s/x_s reads done

        if (tj >= 200 && tj < 300) {
            // n gate + state update (100 threads)
            #pragma unroll
            for (int b = 0; b < BT; ++b) {
                float n  = tanhf_(acc_i[b] + r_s[b][i] * acc_h[b]);
                float z  = z_s[b][i];
                float hn = (1.f - z) * n + z * h_s[b][i];
                h_s[b][i] = hn;
                if (WRITE_SEQ)
                    seq_out[((long)t * TB + bb0 + b) * HH + i] = hn;
            }
        }
        if constexpr (!EMB) {
            if (has_next) {
                if (tj < BT * K) x_s[tj / K][tj % K] = px0;
                if constexpr (BT * K > 320) {
                    if (tj + 320 < BT * K)
                        x_s[(tj + 320) / K][(tj + 320) % K] = px1;
                }
            }
        } else {
            if (has_next && tj < BT) tgt_s[tj] = ptg;
            __syncthreads();   // B2: tgt_s visible
            if (has_next && tj < BT * KP) {
                int b = tj / KP, k = tj % KP;
                x_s[b][k] = emb_s[tgt_s[b]][k];
            }
        }
        __syncthreads();       // step barrier: h_s and x_s ready
    }

    if (h_last != nullptr && tj >= 200 && tj < 300) {
        #pragma unroll
        for (int b = 0; b < BT; ++b)
            h_last[(bb0 + b) * HH + i] = h_s[b][i];
    }
}

// Final linear + argmax + target_cal.
// block = 256 = 4 slots x 64 lanes (lane = output class d, wave = one (p,b) slot)
__global__ __launch_bounds__(256)
void final_kernel(const float* __restrict__ d1,
                  const float* __restrict__ linW,   // [64,100]
                  const float* __restrict__ linb,   // [64]
                  const int*   __restrict__ tgt,    // [80,1024]
                  float* __restrict__ out0,         // [79*1024,64] logits
                  float* __restrict__ out1,         // [79*1024] target_cal
                  float* __restrict__ out2)         // [79*1024] argmax
{
    __shared__ float WT[HH][64];     // WT[k][d]
    __shared__ __align__(16) float row[4][HH];

    const int tid = threadIdx.x;
    for (int idx = tid; idx < 64 * HH; idx += 256) {
        int d = idx / HH, k = idx % HH;
        WT[k][d] = linW[idx];
    }
    const int s    = tid >> 6;
    const int d    = tid & 63;
    const int slot = blockIdx.x * 4 + s;     // < 79*1024
    const int p    = slot >> 10;
    const int b    = slot & 1023;
    const float* drow = &d1[(long)(p * TB + b) * HH];
    __syncthreads();
    if (d < 50) {
        float2 v = *reinterpret_cast<const float2*>(&drow[2 * d]);
        row[s][2 * d]     = v.x;
        row[s][2 * d + 1] = v.y;
    }
    __syncthreads();

    float acc = linb[d];
    #pragma unroll
    for (int k = 0; k < HH; ++k)
        acc += row[s][k] * WT[k][d];

    out0[(long)slot * 64 + d] = acc;

    // argmax over 64 lanes, first-occurrence tie-break (min index among maxima)
    float mv = acc;
    int   mi = d;
    #pragma unroll
    for (int off = 32; off >= 1; off >>= 1) {
        float ov = __shfl_xor(mv, off, 64);
        int   oi = __shfl_xor(mi, off, 64);
        if (ov > mv || (ov == mv && oi < mi)) { mv = ov; mi = oi; }
    }
    if (d == 0) out2[slot] = (float)mi;
    if (d == 1) out1[slot] = (float)tgt[(p + 1) * TB + b];
}

extern "C" void kernel_launch(void* const* d_in, const int* in_sizes, int n_in,
                              void* d_out, int out_size, void* d_ws, size_t ws_size,
                              hipStream_t stream)
{
    const float* x      = (const float*)d_in[0];
    const int*   target = (const int*)  d_in[1];
    const float* emb    = (const float*)d_in[2];
    const float* eWih0  = (const float*)d_in[3];
    const float* eWhh0  = (const float*)d_in[4];
    const float* ebih0  = (const float*)d_in[5];
    const float* ebhh0  = (const float*)d_in[6];
    const float* eWih1  = (const float*)d_in[7];
    const float* eWhh1  = (const float*)d_in[8];
    const float* ebih1  = (const float*)d_in[9];
    const float* ebhh1  = (const float*)d_in[10];
    const float* dWih0  = (const float*)d_in[11];
    const float* dWhh0  = (const float*)d_in[12];
    const float* dbih0  = (const float*)d_in[13];
    const float* dbhh0  = (const float*)d_in[14];
    const float* dWih1  = (const float*)d_in[15];
    const float* dWhh1  = (const float*)d_in[16];
    const float* dbih1  = (const float*)d_in[17];
    const float* dbhh1  = (const float*)d_in[18];
    const float* linW   = (const float*)d_in[19];
    const float* linb   = (const float*)d_in[20];

    // workspace layout (floats):
    //  [0, 102400)                       h_enc0
    //  [102400, 204800)                  h_enc1
    //  [204800, 204800+51.2M)            e0 during encoder
    //  same region reused for d0/d1 during decoder (e0 dead by then)
    float* ws     = (float*)d_ws;
    float* h_enc0 = ws;
    float* h_enc1 = ws + 102400;
    float* e0     = ws + 204800;                      // 500*1024*100
    float* d0     = ws + 204800;                      // aliases e0 (dead)
    float* d1_    = ws + 204800 + 80 * 1024 * 100;    // 80*1024*100

    dim3 grid(256), blk(320);   // 300 gate-rows + 20 pad, BT=4 per block
    // encoder layer 0: raw x input (K=26), write e0 + h_enc0
    gru_kernel<26,  false, true ><<<grid, blk, 0, stream>>>(
        x, nullptr, nullptr, eWih0, eWhh0, ebih0, ebhh0, nullptr, e0, h_enc0, 500);
    // encoder layer 1: e0 input (K=100), only h_enc1 needed
    gru_kernel<100, false, false><<<grid, blk, 0, stream>>>(
        e0, nullptr, nullptr, eWih1, eWhh1, ebih1, ebhh1, nullptr, nullptr, h_enc1, 500);
    // decoder layer 0: embedding-gather input (K=26), h0 = h_enc0
    gru_kernel<26,  true,  true ><<<grid, blk, 0, stream>>>(
        nullptr, target, emb, dWih0, dWhh0, dbih0, dbhh0, h_enc0, d0, nullptr, 80);
    // decoder layer 1: d0 input (K=100), h0 = h_enc1, write d1
    gru_kernel<100, false, true ><<<grid, blk, 0, stream>>>(
        d0, nullptr, nullptr, dWih1, dWhh1, dbih1, dbhh1, h_enc1, d1_, nullptr, 80);

    float* out0 = (float*)d_out;
    float* out1 = out0 + (long)79 * 1024 * 64;
    float* out2 = out1 + 79 * 1024;
    final_kernel<<<dim3(20224), dim3(256), 0, stream>>>(d1_, linW, linb, target,
                                                        out0, out1, out2);
}

// Round 2
// 4421.407 us; speedup vs baseline: 1.0856x; 1.0856x over previous
//
#include <hip/hip_runtime.h>
#include <math.h>
#include <utility>

#define TB 1024   // batch
#define HH 100    // hidden
#define GG 300    // 3*H gate rows

// ---------------------------------------------------------------------------
// NUMERICS ARE FROZEN — DO NOT TOUCH.
// R1 (__expf), R5 (naive exp2), R6 (1-ulp Cody-Waite expm1) ALL flipped the
// same decoder argmax site (absmax=14). Only the ocml expf/tanhf profile
// (R2/R3/R7/R8/R9) lands on the reference side of a knife-edge logit
// near-tie. The transcendentals AND the per-element GEMV/gate expression DAG
// (values, pairing, order) must stay bit-identical. Perf work value-neutral.
// gemv4-for-both-GEMVs DAG proven value-neutral in R11 (passed, absmax same).
//
// R12: the allocator, not the algorithm, was the R9-R11 bottleneck.
// Evidence: VGPR_Count = 84 (R10, launch_bounds(640,3) -> 512/6) and
// 128 (R11, launch_bounds(320,2) -> 512/4): hipcc targets ~2x the declared
// min waves/EU and caps arch VGPRs there. The 100-200 float weight arrays
// overflowed to AGPRs (unified file, invisible in VGPR_Count, no scratch:
// FETCH flat at 105MB) and every in-loop pin forced v_accvgpr_read/write
// pairs -> ~2 extra VALU/element/step. Fix: amdgpu_waves_per_eu(3,3)
// pins the budget at 512/3=170 regs so weights live in ARCH VGPRs.
//   - K=26: 320thr/BT=2/grid512 (2 indep blocks/CU, 10 waves), whh+wih in
//     regs (~160): zero lane-varying LDS, broadcast-only ~1.9K cyc/CU-step.
//   - K=100: R10 640thr/2-team/BT=2/grid256 structure verbatim (120KB whh
//     LDS forbids 2 blocks/CU; 230-reg both-in-regs forbids 10 waves),
//     now with wih[100] actually register-resident.
// ---------------------------------------------------------------------------
__device__ __forceinline__ float sigmoidf_(float x) {
    return 1.0f / (1.0f + expf(-x));
}
__device__ __forceinline__ float tanhf_(float x) {
    return tanhf(x);
}

template<size_t... Is>
__device__ __forceinline__ void ldN(std::index_sequence<Is...>,
                                    float* __restrict__ dst,
                                    const float* __restrict__ src) {
    ((dst[Is] = src[Is]), ...);
}
__device__ __forceinline__ float pin_val(float v) {
    asm volatile("" : "+v"(v));
    return v;
}
// IN-LOOP PIN (R10): non-rematerializable SSA chain -> weights stay resident.
// Free ONLY when values are in arch VGPRs (the waves_per_eu attr ensures it).
template<size_t... Is>
__device__ __forceinline__ void pinN(std::index_sequence<Is...>, float* w) {
    ((w[Is] = pin_val(w[Is])), ...);
}

// acc += w-row (registers) dot vec (LDS broadcast), float4-grouped.
// EXACT expression shape shared by acc_i and acc_h paths (frozen DAG).
template<int KK, int BT, int LD>
__device__ __forceinline__ void fma_step(const float* __restrict__ w,
                                         const float (*xs)[LD],
                                         float* __restrict__ acc) {
    #pragma unroll
    for (int b = 0; b < BT; ++b) {
        const float4 xv = *reinterpret_cast<const float4*>(&xs[b][KK]);
        acc[b] += w[KK]     * xv.x + w[KK + 1] * xv.y
                + w[KK + 2] * xv.z + w[KK + 3] * xv.w;
    }
}
template<int BT, int LD, size_t... Is>
__device__ __forceinline__ void gemv4(std::index_sequence<Is...>,
                                      const float* __restrict__ w,
                                      const float (*xs)[LD],
                                      float* __restrict__ acc) {
    (fma_step<(int)(Is * 4), BT, LD>(w, xs, acc), ...);
}

// acc_h variant: weights from LDS k-packed [grp][row][4], h broadcast from LDS.
// Pairing/order identical to fma_step: wv.x==w[4g+0] pairs hv.x==h[4g+0], ...
template<int GRP, int BT>
__device__ __forceinline__ void fma_lds_step(const float* __restrict__ wl,
                                             int row,
                                             const float (*hs)[HH],
                                             float* __restrict__ acc) {
    const float4 wv = *reinterpret_cast<const float4*>(wl + (GRP * GG + row) * 4);
    #pragma unroll
    for (int b = 0; b < BT; ++b) {
        const float4 hv = *reinterpret_cast<const float4*>(&hs[b][GRP * 4]);
        acc[b] += wv.x * hv.x + wv.y * hv.y + wv.z * hv.z + wv.w * hv.w;
    }
}
template<int BT, size_t... Is>
__device__ __forceinline__ void gemv_lds(std::index_sequence<Is...>,
                                         const float* __restrict__ wl, int row,
                                         const float (*hs)[HH],
                                         float* __restrict__ acc) {
    (fma_lds_step<(int)Is, BT>(wl, row, hs, acc), ...);
}

// ===========================================================================
// Small-K persistent GRU kernel (K=26): 320 threads, BT=2, grid 512.
// Thread = one gate-row; BOTH wih and whh rows in arch VGPRs (~160 <= 170).
// 2 independent blocks/CU -> independent barrier domains hide each other.
// ===========================================================================
template<int K, bool EMB, bool WRITE_SEQ>
__global__ __launch_bounds__(320)
__attribute__((amdgpu_waves_per_eu(3, 3)))
void gru_small(const float* __restrict__ xin,   // [T,B,K] (if !EMB)
               const int*   __restrict__ tgt,   // [T,B]   (if EMB)
               const float* __restrict__ emb,   // [64,26] (if EMB)
               const float* __restrict__ Wih,   // [300,K]
               const float* __restrict__ Whh,   // [300,100]
               const float* __restrict__ bih,
               const float* __restrict__ bhh,
               const float* __restrict__ h_init,// [B,100] or null -> zeros
               float* __restrict__ seq_out,     // [T,B,100] (if WRITE_SEQ)
               float* __restrict__ h_last,      // [B,100] or null
               int T)
{
    constexpr int KP = (K + 3) & ~3;   // 28
    constexpr int BT = 2;              // batch per block
    static_assert(KP % 4 == 0, "");
    static_assert(BT * K <= 320, "");

    const int tj  = threadIdx.x;       // row index (0..319)
    const int bb0 = blockIdx.x * BT;
    const int g   = tj / 100;
    const int i   = tj % 100;

    __shared__ __align__(16) float h_s[BT][HH];
    __shared__ __align__(16) float x_s[BT][KP];
    __shared__ float r_s[BT][HH];
    __shared__ float z_s[BT][HH];
    __shared__ float emb_s[EMB ? 64 : 1][EMB ? 28 : 4];
    __shared__ int   tgt_s[BT];

    // ---- wih + whh rows into registers (one-time, clamped row for pads) ----
    const int jj = (tj < GG) ? tj : 0;
    float wih[KP];
    ldN(std::make_index_sequence<K>{}, wih, Wih + (long)jj * K);
    #pragma unroll
    for (int k = K; k < KP; ++k) wih[k] = 0.f;
    float whr[HH];
    ldN(std::make_index_sequence<HH>{}, whr, Whh + (long)jj * HH);
    float bi = bih[jj];
    float bh = bhh[jj];

    // ---- init h ----
    for (int idx = tj; idx < BT * HH; idx += 320) {
        int b = idx / HH, k = idx % HH;
        h_s[b][k] = h_init ? h_init[(bb0 + b) * HH + k] : 0.f;
    }
    // ---- init x_s for t=0 ----
    if constexpr (EMB) {
        for (int idx = tj; idx < 64 * 28; idx += 320) {
            int d = idx / 28, k = idx % 28;
            emb_s[d][k] = (k < 26) ? emb[d * 26 + k] : 0.f;
        }
        __syncthreads();
        for (int idx = tj; idx < BT * KP; idx += 320) {
            int b = idx / KP, k = idx % KP;
            int t0 = tgt[bb0 + b];
            x_s[b][k] = emb_s[t0][k];    // pads are 0 via emb_s
        }
    } else {
        for (int idx = tj; idx < BT * KP; idx += 320) {
            int b = idx / KP, k = idx % KP;
            x_s[b][k] = (k < K) ? xin[(bb0 + b) * K + k] : 0.f;
        }
    }
    __syncthreads();   // h_s, x_s ready

    // ---- time loop ----
    for (int t = 0; t < T; ++t) {
        pinN(std::make_index_sequence<KP>{}, wih);
        pinN(std::make_index_sequence<HH>{}, whr);
        bi = pin_val(bi);
        bh = pin_val(bh);

        const bool has_next = (t + 1 < T);

        // prefetch next step's input into regs (hidden under FMA loop)
        float px0 = 0.f;
        int   ptg = 0;
        if constexpr (!EMB) {
            if (has_next && tj < BT * K)
                px0 = xin[((t + 1) * TB + bb0 + tj / K) * K + tj % K];
        } else {
            if (has_next && tj < BT) ptg = tgt[(t + 1) * TB + bb0 + tj];
        }

        // main GEMV: acc_i = Wih[j,:].x + bi ; acc_h = Whh[j,:].h + bh
        float acc_i[BT], acc_h[BT];
        #pragma unroll
        for (int b = 0; b < BT; ++b) { acc_i[b] = bi; acc_h[b] = bh; }

        gemv4<BT, KP>(std::make_index_sequence<KP / 4>{}, wih, x_s, acc_i);
        gemv4<BT, HH>(std::make_index_sequence<HH / 4>{}, whr, h_s, acc_h);

        // r / z gates -> LDS
        if (tj < 200) {
            #pragma unroll
            for (int b = 0; b < BT; ++b) {
                float v = sigmoidf_(acc_i[b] + acc_h[b]);
                if (g == 0) r_s[b][i] = v;
                else        z_s[b][i] = v;
            }
        }
        __syncthreads();   // B1: gates visible; h_s/x_s reads done

        if (tj >= 200 && tj < 300) {
            // n gate + state update (100 threads)
            #pragma unroll
            for (int b = 0; b < BT; ++b) {
                float n  = tanhf_(acc_i[b] + r_s[b][i] * acc_h[b]);
                float z  = z_s[b][i];
                float hn = (1.f - z) * n + z * h_s[b][i];
                h_s[b][i] = hn;
                if (WRITE_SEQ)
                    seq_out[((long)t * TB + bb0 + b) * HH + i] = hn;
            }
        }
        if constexpr (!EMB) {
            if (has_next && tj < BT * K) x_s[tj / K][tj % K] = px0;
        } else {
            if (has_next && tj < BT) tgt_s[tj] = ptg;
            __syncthreads();   // B2: tgt_s visible
            if (has_next && tj < BT * KP) {
                int b = tj / KP, k = tj % KP;
                x_s[b][k] = emb_s[tgt_s[b]][k];
            }
        }
        __syncthreads();       // step barrier: h_s and x_s ready
    }

    if (h_last != nullptr && tj >= 200 && tj < 300) {
        #pragma unroll
        for (int b = 0; b < BT; ++b)
            h_last[(bb0 + b) * HH + i] = h_s[b][i];
    }
}

// ===========================================================================
// Big-K persistent GRU kernel (K=100): R10 structure verbatim.
// 640 threads = 2 teams x (300+20), BT=2 per team, grid 256. whh k-packed in
// LDS (120KB -> 1 block/CU), wih row in regs (now ARCH regs via waves attr).
// ===========================================================================
template<int K, bool WRITE_SEQ>
__global__ __launch_bounds__(640)
__attribute__((amdgpu_waves_per_eu(3, 3)))
void gru_big(const float* __restrict__ xin,   // [T,B,K]
             const float* __restrict__ Wih,   // [300,K]
             const float* __restrict__ Whh,   // [300,100]
             const float* __restrict__ bih,
             const float* __restrict__ bhh,
             const float* __restrict__ h_init,// [B,100] or null -> zeros
             float* __restrict__ seq_out,     // [T,B,100] (if WRITE_SEQ)
             float* __restrict__ h_last,      // [B,100] or null
             int T)
{
    constexpr int KP = (K + 3) & ~3;   // 100
    constexpr int BT = 2;              // batch per team
    constexpr int NT = 2;              // teams
    static_assert(KP % 4 == 0, "");

    const int tid  = threadIdx.x;
    const int team = tid / 320;
    const int tj   = tid % 320;        // row index within team (0..319)
    const int bb0  = blockIdx.x * (BT * NT) + team * BT;
    const int g    = tj / 100;
    const int i    = tj % 100;

    __shared__ __align__(16) float whh_l[(HH / 4) * GG * 4];  // 120000 B
    __shared__ __align__(16) float h_s[NT][BT][HH];
    __shared__ __align__(16) float x_s[NT][BT][KP];
    __shared__ float r_s[NT][BT][HH];
    __shared__ float z_s[NT][BT][HH];

    // ---- wih row into registers (one-time, unconditional w/ clamped row) ----
    const int jj = (tj < GG) ? tj : 0;
    float wih[KP];
    ldN(std::make_index_sequence<K>{}, wih, Wih + (long)jj * K);
    #pragma unroll
    for (int k = K; k < KP; ++k) wih[k] = 0.f;
    float bi = bih[jj];
    float bh = bhh[jj];

    // ---- stage whh into LDS, k-packed: whh_l[(k/4)*GG + row][k%4] ----
    for (int idx = tid; idx < GG * HH; idx += 640) {
        int row = idx / HH, k = idx % HH;
        whh_l[((k >> 2) * GG + row) * 4 + (k & 3)] = Whh[row * HH + k];
    }

    // ---- init h (per team) ----
    for (int idx = tj; idx < BT * HH; idx += 320) {
        int b = idx / HH, k = idx % HH;
        h_s[team][b][k] = h_init ? h_init[(bb0 + b) * HH + k] : 0.f;
    }
    // ---- init x_s for t=0 ----
    for (int idx = tj; idx < BT * KP; idx += 320) {
        int b = idx / KP, k = idx % KP;
        x_s[team][b][k] = (k < K) ? xin[(bb0 + b) * K + k] : 0.f;
    }
    __syncthreads();   // whh_l, h_s, x_s ready

    // ---- time loop ----
    for (int t = 0; t < T; ++t) {
        // IN-LOOP PIN: non-rematerializable SSA chain -> wih stays resident.
        pinN(std::make_index_sequence<KP>{}, wih);
        bi = pin_val(bi);
        bh = pin_val(bh);

        const bool has_next = (t + 1 < T);

        // prefetch next step's input into regs (hidden under FMA loop)
        float px = 0.f;
        if (has_next && !(tj >= 200 && tj < 300)) {
            int stid = (tj < 200) ? tj : tj - 100;   // 0..219
            if (stid < BT * K)
                px = xin[((t + 1) * TB + bb0 + stid / K) * K + stid % K];
        }

        // main GEMV: acc_i = Wih[j,:].x + bi ; acc_h = Whh[j,:].h + bh
        float acc_i[BT], acc_h[BT];
        #pragma unroll
        for (int b = 0; b < BT; ++b) { acc_i[b] = bi; acc_h[b] = bh; }

        gemv4<BT, KP>(std::make_index_sequence<KP / 4>{}, wih, x_s[team], acc_i);
        gemv_lds<BT>(std::make_index_sequence<HH / 4>{}, whh_l, jj, h_s[team], acc_h);

        // r / z gates -> LDS
        if (tj < 200) {
            #pragma unroll
            for (int b = 0; b < BT; ++b) {
                float v = sigmoidf_(acc_i[b] + acc_h[b]);
                if (g == 0) r_s[team][b][i] = v;
                else        z_s[team][b][i] = v;
            }
        }
        __syncthreads();   // B1: gates visible

        if (tj >= 200 && tj < 300) {
            // n gate + state update (100 threads per team)
            #pragma unroll
            for (int b = 0; b < BT; ++b) {
                float n  = tanhf_(acc_i[b] + r_s[team][b][i] * acc_h[b]);
                float z  = z_s[team][b][i];
                float hn = (1.f - z) * n + z * h_s[team][b][i];
                h_s[team][b][i] = hn;
                if (WRITE_SEQ)
                    seq_out[((long)t * TB + bb0 + b) * HH + i] = hn;
            }
        } else {
            if (has_next) {
                int stid = (tj < 200) ? tj : tj - 100;
                if (stid < BT * K) x_s[team][stid / K][stid % K] = px;
            }
        }
        __syncthreads();       // step barrier: h_s and x_s ready
    }

    if (h_last != nullptr && tj >= 200 && tj < 300) {
        #pragma unroll
        for (int b = 0; b < BT; ++b)
            h_last[(bb0 + b) * HH + i] = h_s[team][b][i];
    }
}

// Final linear + argmax + target_cal.
// block = 256 = 4 slots x 64 lanes (lane = output class d, wave = one (p,b) slot)
__global__ __launch_bounds__(256)
void final_kernel(const float* __restrict__ d1,
                  const float* __restrict__ linW,   // [64,100]
                  const float* __restrict__ linb,   // [64]
                  const int*   __restrict__ tgt,    // [80,1024]
                  float* __restrict__ out0,         // [79*1024,64] logits
                  float* __restrict__ out1,         // [79*1024] target_cal
                  float* __restrict__ out2)         // [79*1024] argmax
{
    __shared__ float WT[HH][64];     // WT[k][d]
    __shared__ __align__(16) float row[4][HH];

    const int tid = threadIdx.x;
    for (int idx = tid; idx < 64 * HH; idx += 256) {
        int d = idx / HH, k = idx % HH;
        WT[k][d] = linW[idx];
    }
    const int s    = tid >> 6;
    const int d    = tid & 63;
    const int slot = blockIdx.x * 4 + s;     // < 79*1024
    const int p    = slot >> 10;
    const int b    = slot & 1023;
    const float* drow = &d1[(long)(p * TB + b) * HH];
    __syncthreads();
    if (d < 50) {
        float2 v = *reinterpret_cast<const float2*>(&drow[2 * d]);
        row[s][2 * d]     = v.x;
        row[s][2 * d + 1] = v.y;
    }
    __syncthreads();

    float acc = linb[d];
    #pragma unroll
    for (int k = 0; k < HH; ++k)
        acc += row[s][k] * WT[k][d];

    out0[(long)slot * 64 + d] = acc;

    // argmax over 64 lanes, first-occurrence tie-break (min index among maxima)
    float mv = acc;
    int   mi = d;
    #pragma unroll
    for (int off = 32; off >= 1; off >>= 1) {
        float ov = __shfl_xor(mv, off, 64);
        int   oi = __shfl_xor(mi, off, 64);
        if (ov > mv || (ov == mv && oi < mi)) { mv = ov; mi = oi; }
    }
    if (d == 0) out2[slot] = (float)mi;
    if (d == 1) out1[slot] = (float)tgt[(p + 1) * TB + b];
}

extern "C" void kernel_launch(void* const* d_in, const int* in_sizes, int n_in,
                              void* d_out, int out_size, void* d_ws, size_t ws_size,
                              hipStream_t stream)
{
    const float* x      = (const float*)d_in[0];
    const int*   target = (const int*)  d_in[1];
    const float* emb    = (const float*)d_in[2];
    const float* eWih0  = (const float*)d_in[3];
    const float* eWhh0  = (const float*)d_in[4];
    const float* ebih0  = (const float*)d_in[5];
    const float* ebhh0  = (const float*)d_in[6];
    const float* eWih1  = (const float*)d_in[7];
    const float* eWhh1  = (const float*)d_in[8];
    const float* ebih1  = (const float*)d_in[9];
    const float* ebhh1  = (const float*)d_in[10];
    const float* dWih0  = (const float*)d_in[11];
    const float* dWhh0  = (const float*)d_in[12];
    const float* dbih0  = (const float*)d_in[13];
    const float* dbhh0  = (const float*)d_in[14];
    const float* dWih1  = (const float*)d_in[15];
    const float* dWhh1  = (const float*)d_in[16];
    const float* dbih1  = (const float*)d_in[17];
    const float* dbhh1  = (const float*)d_in[18];
    const float* linW   = (const float*)d_in[19];
    const float* linb   = (const float*)d_in[20];

    // workspace layout (floats):
    //  [0, 102400)                       h_enc0
    //  [102400, 204800)                  h_enc1
    //  [204800, 204800+51.2M)            e0 during encoder
    //  same region reused for d0/d1 during decoder (e0 dead by then)
    float* ws     = (float*)d_ws;
    float* h_enc0 = ws;
    float* h_enc1 = ws + 102400;
    float* e0     = ws + 204800;                      // 500*1024*100
    float* d0     = ws + 204800;                      // aliases e0 (dead)
    float* d1_    = ws + 204800 + 80 * 1024 * 100;    // 80*1024*100

    // encoder layer 0: raw x input (K=26), write e0 + h_enc0
    gru_small<26, false, true ><<<dim3(512), dim3(320), 0, stream>>>(
        x, nullptr, nullptr, eWih0, eWhh0, ebih0, ebhh0, nullptr, e0, h_enc0, 500);
    // encoder layer 1: e0 input (K=100), only h_enc1 needed
    gru_big<100, false><<<dim3(256), dim3(640), 0, stream>>>(
        e0, eWih1, eWhh1, ebih1, ebhh1, nullptr, nullptr, h_enc1, 500);
    // decoder layer 0: embedding-gather input (K=26), h0 = h_enc0
    gru_small<26, true,  true ><<<dim3(512), dim3(320), 0, stream>>>(
        nullptr, target, emb, dWih0, dWhh0, dbih0, dbhh0, h_enc0, d0, nullptr, 80);
    // decoder layer 1: d0 input (K=100), h0 = h_enc1, write d1
    gru_big<100, true ><<<dim3(256), dim3(640), 0, stream>>>(
        d0, dWih1, dWhh1, dbih1, dbhh1, h_enc1, d1_, nullptr, 80);

    float* out0 = (float*)d_out;
    float* out1 = out0 + (long)79 * 1024 * 64;
    float* out2 = out1 + 79 * 1024;
    final_kernel<<<dim3(20224), dim3(256), 0, stream>>>(d1_, linW, linb, target,
                                                        out0, out1, out2);
}